// Round 1
// baseline (2831.066 us; speedup 1.0000x reference)
//
#include <hip/hip_runtime.h>
#include <math.h>

#define TILE 64
#define KTS 16
#define PAD 4   // row stride TILE+4 = 68 floats = 272 B, multiple of 16 B -> ds_read_b128 ok

// GEMM: out[b][m][n] = bias[m] + sum_q A[m][q] * Bmat[b][q][n]
// A = weights (M x K) row-major (O, C*9) with q = c*9 + (ky*3+kx).
// Bmat: explicit cols [b][K][N] if !IMPLICIT, else implicit im2col of
//       X = x + up2(prev) with zero padding (3x3, pad 1).
template<bool IMPLICIT>
__global__ __launch_bounds__(256) void gemm_kernel(
    const float* __restrict__ Wmat, const float* __restrict__ bias,
    const float* __restrict__ Bsrc,   // cols if !IMPLICIT, x if IMPLICIT
    const float* __restrict__ prev,   // t_{lvl+1} or nullptr
    float* __restrict__ outp,
    int M, int N, int K, int H, int W, int Hp, int Wp, int C)
{
    __shared__ float As[KTS][TILE + PAD];
    __shared__ float Bs[KTS][TILE + PAD];
    const int b  = blockIdx.z;
    const int m0 = blockIdx.y * TILE;
    const int n0 = blockIdx.x * TILE;
    const int tid = threadIdx.x;          // 0..255
    const int tx = tid & 15, ty = tid >> 4;

    float acc[4][4] = {};

    const float* xb    = IMPLICIT ? (Bsrc + (size_t)b * C * H * W) : nullptr;
    const float* pb    = (prev != nullptr) ? (prev + (size_t)b * C * Hp * Wp) : nullptr;
    const float* colsb = IMPLICIT ? nullptr : (Bsrc + (size_t)b * (size_t)K * N);

    for (int kt = 0; kt < K; kt += KTS) {
        // ---- load A tile (64 rows of W, 16 K's) : 1024 elems, 4/thread
        #pragma unroll
        for (int i = 0; i < 4; ++i) {
            int e  = tid + i * 256;
            int kk = e & 15;
            int mm = e >> 4;
            float v = 0.f;
            if (m0 + mm < M) v = Wmat[(size_t)(m0 + mm) * K + kt + kk];
            As[kk][mm] = v;
        }
        // ---- load B tile (16 K's x 64 n's)
        #pragma unroll
        for (int i = 0; i < 4; ++i) {
            int e  = tid + i * 256;
            int nn = e & 63;
            int kk = e >> 6;
            int n  = n0 + nn;
            float v = 0.f;
            if (n < N) {
                int q = kt + kk;
                if (!IMPLICIT) {
                    v = colsb[(size_t)q * N + n];
                } else {
                    int c = q / 9, r = q % 9;
                    int ky = r / 3 - 1, kx = r % 3 - 1;
                    int h = n / W, w = n % W;
                    int ih = h + ky, iw = w + kx;
                    if (ih >= 0 && ih < H && iw >= 0 && iw < W) {
                        v = xb[(size_t)c * H * W + ih * W + iw];
                        if (pb) v += pb[(size_t)c * Hp * Wp + (ih >> 1) * Wp + (iw >> 1)];
                    }
                }
            }
            Bs[kk][nn] = v;
        }
        __syncthreads();

        #pragma unroll
        for (int kk = 0; kk < KTS; ++kk) {
            float a[4], bb[4];
            #pragma unroll
            for (int i = 0; i < 4; ++i) a[i] = As[kk][ty * 4 + i];
            #pragma unroll
            for (int j = 0; j < 4; ++j) bb[j] = Bs[kk][tx * 4 + j];
            #pragma unroll
            for (int i = 0; i < 4; ++i)
                #pragma unroll
                for (int j = 0; j < 4; ++j)
                    acc[i][j] += a[i] * bb[j];
        }
        __syncthreads();
    }

    #pragma unroll
    for (int i = 0; i < 4; ++i) {
        int m = m0 + ty * 4 + i;
        if (m >= M) continue;
        float bs = bias ? bias[m] : 0.f;
        #pragma unroll
        for (int j = 0; j < 4; ++j) {
            int n = n0 + tx * 4 + j;
            if (n < N) outp[((size_t)b * M + m) * (size_t)N + n] = acc[i][j] + bs;
        }
    }
}

// Deformable bilinear sampling + mask -> cols[b][c*9+k][hw]
__global__ __launch_bounds__(256) void sampling_kernel(
    const float* __restrict__ x, const float* __restrict__ prev,
    const float* __restrict__ off, float* __restrict__ cols,
    int C, int H, int W, int Hp, int Wp, int B)
{
    const int HW = H * W;
    const int total = B * 9 * HW;
    int idx = blockIdx.x * blockDim.x + threadIdx.x;
    if (idx >= total) return;
    int hw = idx % HW;
    int k  = (idx / HW) % 9;
    int b  = idx / (9 * HW);
    int h = hw / W, w = hw % W;

    // channel map: dy <- conv ch {0,2,..,16}, dx <- {1,3,..,17}, mask <- 18+k
    const int dyc[9] = {0,2,4,6,8,10,12,14,16};
    const int dxc[9] = {1,3,5,7,9,11,13,15,17};

    const float* offb = off + (size_t)b * 27 * HW;
    float dy = offb[(size_t)dyc[k] * HW + hw];
    float dx = offb[(size_t)dxc[k] * HW + hw];
    float mv = offb[(size_t)(18 + k) * HW + hw];
    float m  = 1.0f / (1.0f + expf(-mv));

    float py = (float)h - 1.0f + (float)(k / 3) + dy;
    float px = (float)w - 1.0f + (float)(k % 3) + dx;
    float y0f = floorf(py), x0f = floorf(px);
    float wy = py - y0f, wx = px - x0f;
    int y0 = (int)y0f, x0 = (int)x0f;
    int y1 = y0 + 1,   x1 = x0 + 1;
    bool vy0 = (y0 >= 0) & (y0 < H), vy1 = (y1 >= 0) & (y1 < H);
    bool vx0 = (x0 >= 0) & (x0 < W), vx1 = (x1 >= 0) & (x1 < W);
    bool v00 = vy0 & vx0, v01 = vy0 & vx1, v10 = vy1 & vx0, v11 = vy1 & vx1;
    float w00 = (1.f - wy) * (1.f - wx);
    float w01 = (1.f - wy) * wx;
    float w10 = wy * (1.f - wx);
    float w11 = wy * wx;

    // clamped offsets (used only when valid)
    int cy0 = min(max(y0, 0), H - 1), cy1 = min(max(y1, 0), H - 1);
    int cx0 = min(max(x0, 0), W - 1), cx1 = min(max(x1, 0), W - 1);
    int o00 = cy0 * W + cx0, o01 = cy0 * W + cx1;
    int o10 = cy1 * W + cx0, o11 = cy1 * W + cx1;
    int p00 = (cy0 >> 1) * Wp + (cx0 >> 1), p01 = (cy0 >> 1) * Wp + (cx1 >> 1);
    int p10 = (cy1 >> 1) * Wp + (cx0 >> 1), p11 = (cy1 >> 1) * Wp + (cx1 >> 1);

    float* colp = cols + (((size_t)b * C) * 9 + k) * HW + hw;
    const float* xp = x + (size_t)b * C * HW;
    const float* pp = prev ? prev + (size_t)b * C * Hp * Wp : nullptr;

    for (int c = 0; c < C; ++c) {
        float g00 = v00 ? xp[o00] : 0.f;
        float g01 = v01 ? xp[o01] : 0.f;
        float g10 = v10 ? xp[o10] : 0.f;
        float g11 = v11 ? xp[o11] : 0.f;
        if (pp) {
            if (v00) g00 += pp[p00];
            if (v01) g01 += pp[p01];
            if (v10) g10 += pp[p10];
            if (v11) g11 += pp[p11];
        }
        float v = g00 * w00 + g01 * w01 + g10 * w10 + g11 * w11;
        colp[(size_t)c * 9 * HW] = v * m;
        xp += HW;
        if (pp) pp += (size_t)Hp * Wp;
    }
}

extern "C" void kernel_launch(void* const* d_in, const int* in_sizes, int n_in,
                              void* d_out, int out_size, void* d_ws, size_t ws_size,
                              hipStream_t stream)
{
    // setup_inputs() dict order:
    // x0..x3, (w0,b0),(w1,b1),(w2,b2),(w3,b3), (ow1,ob1),(ow2,ob2),(ow3,ob3)
    const float* x[4]   = {(const float*)d_in[0], (const float*)d_in[1],
                           (const float*)d_in[2], (const float*)d_in[3]};
    const float* wgt[4] = {(const float*)d_in[4], (const float*)d_in[6],
                           (const float*)d_in[8], (const float*)d_in[10]};
    const float* bia[4] = {(const float*)d_in[5], (const float*)d_in[7],
                           (const float*)d_in[9], (const float*)d_in[11]};
    const float* owt[4] = {nullptr, (const float*)d_in[12],
                           (const float*)d_in[14], (const float*)d_in[16]};
    const float* obv[4] = {nullptr, (const float*)d_in[13],
                           (const float*)d_in[15], (const float*)d_in[17]};

    const int B = 2, C = 256, K = 2304;
    const int Hs[4] = {96, 48, 24, 12};

    float* out = (float*)d_out;
    size_t outOff[4];
    outOff[0] = 0;
    outOff[1] = outOff[0] + (size_t)B * C * 96 * 96;
    outOff[2] = outOff[1] + (size_t)B * C * 48 * 48;
    outOff[3] = outOff[2] + (size_t)B * C * 24 * 24;

    // workspace: cols (max level 1: B*2304*2304 floats = 42.5 MB) + off buffer
    float* cols   = (float*)d_ws;
    size_t colsEl = (size_t)B * C * 9 * 48 * 48;
    float* offbuf = cols + colsEl;

    for (int lvl = 3; lvl >= 1; --lvl) {
        int H = Hs[lvl], W = H, HW = H * W;
        const float* prev = (lvl == 3) ? nullptr : (out + outOff[lvl + 1]);
        int Hp = (lvl == 3) ? 1 : Hs[lvl + 1];

        // offset conv: implicit-im2col GEMM, M=27
        {
            dim3 grd((HW + TILE - 1) / TILE, 1, B);
            gemm_kernel<true><<<grd, 256, 0, stream>>>(
                owt[lvl], obv[lvl], x[lvl], prev, offbuf,
                27, HW, K, H, W, Hp, Hp, C);
        }
        // deformable sampling -> cols
        {
            int tot = B * 9 * HW;
            sampling_kernel<<<(tot + 255) / 256, 256, 0, stream>>>(
                x[lvl], prev, offbuf, cols, C, H, W, Hp, Hp, B);
        }
        // main conv: explicit-cols GEMM, M=256
        {
            dim3 grd((HW + TILE - 1) / TILE, 256 / TILE, B);
            gemm_kernel<false><<<grd, 256, 0, stream>>>(
                wgt[lvl], bia[lvl], cols, nullptr, out + outOff[lvl],
                256, HW, K, H, W, Hp, Hp, C);
        }
    }

    // level 0: plain 3x3 conv as implicit-im2col GEMM, input x0 + up2(t1)
    {
        int H = 96, W = 96, HW = H * W;
        const float* prev = out + outOff[1];
        dim3 grd((HW + TILE - 1) / TILE, 256 / TILE, B);
        gemm_kernel<true><<<grd, 256, 0, stream>>>(
            wgt[0], bia[0], x[0], prev, out + outOff[0],
            256, HW, K, H, W, 48, 48, C);
    }
}

// Round 2
// 1638.788 us; speedup vs baseline: 1.7275x; 1.7275x over previous
//
#include <hip/hip_runtime.h>
#include <math.h>

// ---------- helpers ----------
__device__ __forceinline__ ushort f2bf(float f) {
    unsigned int u = __float_as_uint(f);
    u += 0x7FFFu + ((u >> 16) & 1u);   // round-to-nearest-even
    return (ushort)(u >> 16);
}

typedef __attribute__((address_space(1))) const unsigned int guint;
typedef __attribute__((address_space(3))) unsigned int luint;
__device__ __forceinline__ void gload_lds16(const void* g, void* l) {
    __builtin_amdgcn_global_load_lds((guint*)g, (luint*)l, 16, 0, 0);
}

using bfrag = __attribute__((ext_vector_type(8))) short;   // 8 bf16 = 4 VGPR
using f4    = __attribute__((ext_vector_type(4))) float;

// ---------- weight fp32 -> bf16 conversion (7 tensors in one launch) ----------
struct CvtArgs {
    const float* src[7];
    ushort*      dst[7];
    int          n[7];
};
__global__ __launch_bounds__(256) void cvt_kernel(CvtArgs a) {
    int t = blockIdx.y;
    int i = (blockIdx.x * 256 + threadIdx.x) * 4;
    if (i < a.n[t]) {
        float4 v = *(const float4*)&a.src[t][i];
        ushort4 o;
        o.x = f2bf(v.x); o.y = f2bf(v.y); o.z = f2bf(v.z); o.w = f2bf(v.w);
        *(ushort4*)&a.dst[t][i] = o;
    }
}

// ---------- xsum0 = bf16(x0 + up2(t1)) ----------
__global__ __launch_bounds__(256) void xsum_kernel(
    const float* __restrict__ x0, const float* __restrict__ t1,
    ushort* __restrict__ xs, int BC, int H, int W)
{
    int idx = blockIdx.x * 256 + threadIdx.x;       // over BC*H*(W/2)
    int W2 = W >> 1;
    int total = BC * H * W2;
    if (idx >= total) return;
    int wp = idx % W2;
    int rest = idx / W2;
    int h = rest % H, bc = rest / H;
    float2 xv = *(const float2*)&x0[((size_t)bc * H + h) * W + wp * 2];
    float tv = t1[((size_t)bc * (H >> 1) + (h >> 1)) * W2 + wp];
    unsigned int pack = (unsigned int)f2bf(xv.x + tv) |
                        ((unsigned int)f2bf(xv.y + tv) << 16);
    ((unsigned int*)xs)[idx] = pack;
}

// ---------- fp32 implicit-im2col GEMM for the 27-ch offset conv ----------
#define TILE 64
#define KTS 16
#define PADF 4
__global__ __launch_bounds__(256) void off_gemm_f32(
    const float* __restrict__ Wmat, const float* __restrict__ bias,
    const float* __restrict__ x, const float* __restrict__ prev,
    float* __restrict__ outp,
    int M, int N, int K, int H, int W, int Hp, int Wp, int C)
{
    __shared__ float As[KTS][TILE + PADF];
    __shared__ float Bs[KTS][TILE + PADF];
    const int b  = blockIdx.z;
    const int m0 = blockIdx.y * TILE;
    const int n0 = blockIdx.x * TILE;
    const int tid = threadIdx.x;
    const int tx = tid & 15, ty = tid >> 4;

    float acc[4][4] = {};
    const float* xb = x + (size_t)b * C * H * W;
    const float* pb = prev ? prev + (size_t)b * C * Hp * Wp : nullptr;

    for (int kt = 0; kt < K; kt += KTS) {
        #pragma unroll
        for (int i = 0; i < 4; ++i) {
            int e = tid + i * 256;
            int kk = e & 15, mm = e >> 4;
            float v = 0.f;
            if (m0 + mm < M) v = Wmat[(size_t)(m0 + mm) * K + kt + kk];
            As[kk][mm] = v;
        }
        #pragma unroll
        for (int i = 0; i < 4; ++i) {
            int e = tid + i * 256;
            int nn = e & 63, kk = e >> 6;
            int n = n0 + nn;
            float v = 0.f;
            if (n < N) {
                int q = kt + kk;
                int c = q / 9, r = q % 9;
                int ky = r / 3 - 1, kx = r % 3 - 1;
                int h = n / W, w = n % W;
                int ih = h + ky, iw = w + kx;
                if (ih >= 0 && ih < H && iw >= 0 && iw < W) {
                    v = xb[(size_t)c * H * W + ih * W + iw];
                    if (pb) v += pb[(size_t)c * Hp * Wp + (ih >> 1) * Wp + (iw >> 1)];
                }
            }
            Bs[kk][nn] = v;
        }
        __syncthreads();
        #pragma unroll
        for (int kk = 0; kk < KTS; ++kk) {
            float a[4], bb[4];
            #pragma unroll
            for (int i = 0; i < 4; ++i) a[i] = As[kk][ty * 4 + i];
            #pragma unroll
            for (int j = 0; j < 4; ++j) bb[j] = Bs[kk][tx * 4 + j];
            #pragma unroll
            for (int i = 0; i < 4; ++i)
                #pragma unroll
                for (int j = 0; j < 4; ++j)
                    acc[i][j] += a[i] * bb[j];
        }
        __syncthreads();
    }
    #pragma unroll
    for (int i = 0; i < 4; ++i) {
        int m = m0 + ty * 4 + i;
        if (m >= M) continue;
        float bs = bias[m];
        #pragma unroll
        for (int j = 0; j < 4; ++j) {
            int n = n0 + tx * 4 + j;
            if (n < N) outp[((size_t)b * M + m) * (size_t)N + n] = acc[i][j] + bs;
        }
    }
}

// ---------- deformable sampling -> cols[b][n][q] bf16, q = c*9+k ----------
// grid: (ceil(HW/256), C/32, B), block 256 (one thread per hw)
__global__ __launch_bounds__(256) void sampling_kernel(
    const float* __restrict__ x, const float* __restrict__ prev,
    const float* __restrict__ off, ushort* __restrict__ cols,
    int C, int H, int W, int Hp, int Wp)
{
    const int HW = H * W;
    const int HpWp = Hp * Wp;
    const size_t Kk = (size_t)C * 9;
    int b = blockIdx.z;
    int c0 = blockIdx.y * 32;
    int hw = blockIdx.x * 256 + threadIdx.x;
    bool active = hw < HW;
    if (!active) hw = HW - 1;
    int h = hw / W, w = hw % W;

    const float* offb = off + (size_t)b * 27 * HW;
    float w00[9], w01[9], w10[9], w11[9];
    int o00[9], o01[9], o10[9], o11[9];
    int p00[9], p01[9], p10[9], p11[9];
    #pragma unroll
    for (int k = 0; k < 9; ++k) {
        float dy = offb[(size_t)(2 * k) * HW + hw];
        float dx = offb[(size_t)(2 * k + 1) * HW + hw];
        float mv = offb[(size_t)(18 + k) * HW + hw];
        float mk = 1.0f / (1.0f + __expf(-mv));
        float py = (float)h - 1.0f + (float)(k / 3) + dy;
        float px = (float)w - 1.0f + (float)(k % 3) + dx;
        float y0f = floorf(py), x0f = floorf(px);
        float wy = py - y0f, wx = px - x0f;
        int y0 = (int)y0f, x0i = (int)x0f;
        int y1 = y0 + 1, x1 = x0i + 1;
        bool vy0 = (y0 >= 0) & (y0 < H), vy1 = (y1 >= 0) & (y1 < H);
        bool vx0 = (x0i >= 0) & (x0i < W), vx1 = (x1 >= 0) & (x1 < W);
        // fold validity AND mask into the bilinear weights
        w00[k] = (1.f - wy) * (1.f - wx) * ((vy0 & vx0) ? mk : 0.f);
        w01[k] = (1.f - wy) * wx        * ((vy0 & vx1) ? mk : 0.f);
        w10[k] = wy * (1.f - wx)        * ((vy1 & vx0) ? mk : 0.f);
        w11[k] = wy * wx                * ((vy1 & vx1) ? mk : 0.f);
        int cy0 = min(max(y0, 0), H - 1), cy1 = min(max(y1, 0), H - 1);
        int cx0 = min(max(x0i, 0), W - 1), cx1 = min(max(x1, 0), W - 1);
        o00[k] = cy0 * W + cx0; o01[k] = cy0 * W + cx1;
        o10[k] = cy1 * W + cx0; o11[k] = cy1 * W + cx1;
        p00[k] = (cy0 >> 1) * Wp + (cx0 >> 1); p01[k] = (cy0 >> 1) * Wp + (cx1 >> 1);
        p10[k] = (cy1 >> 1) * Wp + (cx0 >> 1); p11[k] = (cy1 >> 1) * Wp + (cx1 >> 1);
    }

    const float* xp = x + ((size_t)b * C + c0) * HW;
    const float* pp = prev ? prev + ((size_t)b * C + c0) * HpWp : nullptr;
    ushort* colp = cols + ((size_t)b * HW + hw) * Kk + (size_t)c0 * 9;

    for (int cc = 0; cc < 32; cc += 8) {
        ushort buf[72];
        if (pp) {
            #pragma unroll
            for (int c8 = 0; c8 < 8; ++c8) {
                const float* xc = xp + (size_t)(cc + c8) * HW;
                const float* pc = pp + (size_t)(cc + c8) * HpWp;
                #pragma unroll
                for (int k = 0; k < 9; ++k) {
                    float g00 = xc[o00[k]] + pc[p00[k]];
                    float g01 = xc[o01[k]] + pc[p01[k]];
                    float g10 = xc[o10[k]] + pc[p10[k]];
                    float g11 = xc[o11[k]] + pc[p11[k]];
                    buf[c8 * 9 + k] = f2bf(g00 * w00[k] + g01 * w01[k] +
                                           g10 * w10[k] + g11 * w11[k]);
                }
            }
        } else {
            #pragma unroll
            for (int c8 = 0; c8 < 8; ++c8) {
                const float* xc = xp + (size_t)(cc + c8) * HW;
                #pragma unroll
                for (int k = 0; k < 9; ++k) {
                    float g00 = xc[o00[k]];
                    float g01 = xc[o01[k]];
                    float g10 = xc[o10[k]];
                    float g11 = xc[o11[k]];
                    buf[c8 * 9 + k] = f2bf(g00 * w00[k] + g01 * w01[k] +
                                           g10 * w10[k] + g11 * w11[k]);
                }
            }
        }
        if (active) {
            uint4* dst = (uint4*)(colp + (size_t)cc * 9);  // 144 B, 16B-aligned
            #pragma unroll
            for (int t = 0; t < 9; ++t) dst[t] = ((uint4*)buf)[t];
        }
    }
}

// ---------- bf16 MFMA GEMM (m97-style, TN: A[M][K], Bt[N][K]) ----------
// IMPLICIT: Bt is xsum bf16 [b][C][H][W], B-operand built by im2col in staging.
template<bool IMPLICIT>
__global__ __launch_bounds__(256) void mfma_gemm(
    const ushort* __restrict__ A, const float* __restrict__ bias,
    const ushort* __restrict__ Bt, float* __restrict__ outp,
    int M, int N, int K, int H, int W)
{
    __shared__ __align__(16) ushort As[128 * 32];
    __shared__ __align__(16) ushort Bs[128 * 32];
    const int b  = blockIdx.z;
    const int m0 = blockIdx.y * 128;
    const int n0 = blockIdx.x * 128;
    const int tid  = threadIdx.x;
    const int lane = tid & 63;
    const int wv   = tid >> 6;
    const int wm = wv >> 1, wn = wv & 1;
    const int C = K / 9;

    f4 acc[4][4] = {};

    const ushort* Bb = IMPLICIT ? Bt + (size_t)b * C * H * W
                                : Bt + (size_t)b * (size_t)N * K;

    for (int kt = 0; kt < K; kt += 32) {
        // ---- stage A tile [128 m][32 k] : 512 x 16B chunks via global_load_lds
        #pragma unroll
        for (int j = 0; j < 2; ++j) {
            int i = j * 256 + tid;
            int row = i >> 2, kc = (i & 3) * 8;
            const ushort* g = A + (size_t)(m0 + row) * K + kt + kc;
            gload_lds16(g, (char*)As + (size_t)(j * 256 + (tid & ~63)) * 16);
        }
        // ---- stage B tile [128 n][32 k]
        if (!IMPLICIT) {
            #pragma unroll
            for (int j = 0; j < 2; ++j) {
                int i = j * 256 + tid;
                int row = i >> 2, kc = (i & 3) * 8;
                int n = n0 + row; if (n >= N) n = N - 1;
                const ushort* g = Bb + (size_t)n * K + kt + kc;
                gload_lds16(g, (char*)Bs + (size_t)(j * 256 + (tid & ~63)) * 16);
            }
        } else {
            #pragma unroll
            for (int j = 0; j < 2; ++j) {
                int ci = j * 256 + tid;
                int row = ci >> 2, kc = (ci & 3) * 8;
                int n = n0 + row; if (n >= N) n = N - 1;
                int h = n / W, w = n % W;
                ushort vals[8];
                #pragma unroll
                for (int t = 0; t < 8; ++t) {
                    int q = kt + kc + t;
                    int c = q / 9, r = q - c * 9;
                    int ih = h + r / 3 - 1, iw = w + r % 3 - 1;
                    ushort v = 0;
                    if (ih >= 0 && ih < H && iw >= 0 && iw < W)
                        v = Bb[((size_t)c * H + ih) * W + iw];
                    vals[t] = v;
                }
                *(uint4*)((char*)Bs + (size_t)ci * 16) = *(uint4*)vals;
            }
        }
        __syncthreads();

        bfrag af[4], bf[4];
        #pragma unroll
        for (int i = 0; i < 4; ++i)
            af[i] = *(const bfrag*)&As[(wm * 64 + i * 16 + (lane & 15)) * 32 + (lane >> 4) * 8];
        #pragma unroll
        for (int j = 0; j < 4; ++j)
            bf[j] = *(const bfrag*)&Bs[(wn * 64 + j * 16 + (lane & 15)) * 32 + (lane >> 4) * 8];
        #pragma unroll
        for (int i = 0; i < 4; ++i)
            #pragma unroll
            for (int j = 0; j < 4; ++j)
                acc[i][j] = __builtin_amdgcn_mfma_f32_16x16x32_bf16(af[i], bf[j], acc[i][j], 0, 0, 0);
        __syncthreads();
    }

    const int mb = m0 + wm * 64, nb = n0 + wn * 64;
    #pragma unroll
    for (int i = 0; i < 4; ++i) {
        int mrow = mb + i * 16 + (lane >> 4) * 4;
        #pragma unroll
        for (int j = 0; j < 4; ++j) {
            int n = nb + j * 16 + (lane & 15);
            if (n < N) {
                #pragma unroll
                for (int t = 0; t < 4; ++t) {
                    int m = mrow + t;
                    outp[((size_t)b * M + m) * (size_t)N + n] = acc[i][j][t] + bias[m];
                }
            }
        }
    }
}

// ---------- host launch ----------
extern "C" void kernel_launch(void* const* d_in, const int* in_sizes, int n_in,
                              void* d_out, int out_size, void* d_ws, size_t ws_size,
                              hipStream_t stream)
{
    const float* x[4]   = {(const float*)d_in[0], (const float*)d_in[1],
                           (const float*)d_in[2], (const float*)d_in[3]};
    const float* wgt[4] = {(const float*)d_in[4], (const float*)d_in[6],
                           (const float*)d_in[8], (const float*)d_in[10]};
    const float* bia[4] = {(const float*)d_in[5], (const float*)d_in[7],
                           (const float*)d_in[9], (const float*)d_in[11]};
    const float* owt[4] = {nullptr, (const float*)d_in[12],
                           (const float*)d_in[14], (const float*)d_in[16]};
    const float* obv[4] = {nullptr, (const float*)d_in[13],
                           (const float*)d_in[15], (const float*)d_in[17]};

    const int B = 2, C = 256, K = 2304;
    const int Hs[4] = {96, 48, 24, 12};

    float* out = (float*)d_out;
    size_t outOff[4];
    outOff[0] = 0;
    outOff[1] = outOff[0] + (size_t)B * C * 96 * 96;
    outOff[2] = outOff[1] + (size_t)B * C * 48 * 48;
    outOff[3] = outOff[2] + (size_t)B * C * 24 * 24;

    // ---- ws carve (bytes, 256-aligned): bf16 weights | cols | xsum0 | offbuf
    char* ws = (char*)d_ws;
    size_t off = 0;
    auto carve = [&](size_t bytes) { void* p = ws + off; off = (off + bytes + 255) & ~(size_t)255; return p; };
    ushort* wbf[4];
    ushort* owbf[4] = {nullptr, nullptr, nullptr, nullptr};
    const int WN = 256 * K, OWN = 27 * K;
    for (int i = 0; i < 4; ++i) wbf[i] = (ushort*)carve((size_t)WN * 2);
    for (int i = 1; i < 4; ++i) owbf[i] = (ushort*)carve((size_t)OWN * 2);
    ushort* cols  = (ushort*)carve((size_t)B * 48 * 48 * K * 2);   // max: level 1
    ushort* xsum0 = (ushort*)carve((size_t)B * C * 96 * 96 * 2);
    float*  offbuf = (float*)carve((size_t)B * 27 * 48 * 48 * 4);

    // ---- convert all 7 weight tensors to bf16 (one launch)
    {
        CvtArgs a;
        a.src[0] = wgt[0]; a.src[1] = wgt[1]; a.src[2] = wgt[2]; a.src[3] = wgt[3];
        a.src[4] = owt[1]; a.src[5] = owt[2]; a.src[6] = owt[3];
        a.dst[0] = wbf[0]; a.dst[1] = wbf[1]; a.dst[2] = wbf[2]; a.dst[3] = wbf[3];
        a.dst[4] = owbf[1]; a.dst[5] = owbf[2]; a.dst[6] = owbf[3];
        for (int i = 0; i < 4; ++i) a.n[i] = WN;
        for (int i = 4; i < 7; ++i) a.n[i] = OWN;
        dim3 grd((WN / 4 + 255) / 256, 7);
        cvt_kernel<<<grd, 256, 0, stream>>>(a);
    }

    for (int lvl = 3; lvl >= 1; --lvl) {
        int H = Hs[lvl], W = H, HW = H * W;
        const float* prev = (lvl == 3) ? nullptr : (out + outOff[lvl + 1]);
        int Hp = (lvl == 3) ? 1 : Hs[lvl + 1];

        // offset conv (fp32, exact geometry)
        {
            dim3 grd((HW + TILE - 1) / TILE, 1, B);
            off_gemm_f32<<<grd, 256, 0, stream>>>(
                owt[lvl], obv[lvl], x[lvl], prev, offbuf,
                27, HW, K, H, W, Hp, Hp, C);
        }
        // deformable sampling -> cols [b][n][q] bf16
        {
            dim3 grd((HW + 255) / 256, C / 32, B);
            sampling_kernel<<<grd, 256, 0, stream>>>(
                x[lvl], prev, offbuf, cols, C, H, W, Hp, Hp);
        }
        // main conv: bf16 MFMA GEMM, explicit cols
        {
            dim3 grd((HW + 127) / 128, 2, B);
            mfma_gemm<false><<<grd, 256, 0, stream>>>(
                wbf[lvl], bia[lvl], cols, out + outOff[lvl],
                256, HW, K, H, W);
        }
    }

    // level 0: xsum = bf16(x0 + up2(t1)), then implicit-im2col MFMA GEMM
    {
        int H = 96, W = 96, HW = H * W;
        int total = B * C * H * (W / 2);
        xsum_kernel<<<(total + 255) / 256, 256, 0, stream>>>(
            x[0], out + outOff[1], xsum0, B * C, H, W);
        dim3 grd((HW + 127) / 128, 2, B);
        mfma_gemm<true><<<grd, 256, 0, stream>>>(
            wbf[0], bia[0], xsum0, out + outOff[0],
            256, HW, K, H, W);
    }
}

// Round 3
// 615.650 us; speedup vs baseline: 4.5985x; 2.6619x over previous
//
#include <hip/hip_runtime.h>
#include <math.h>

// ---------- helpers ----------
__device__ __forceinline__ ushort f2bf(float f) {
    unsigned int u = __float_as_uint(f);
    u += 0x7FFFu + ((u >> 16) & 1u);   // round-to-nearest-even
    return (ushort)(u >> 16);
}
__device__ __forceinline__ float bf2f(ushort u) {
    return __uint_as_float((unsigned int)u << 16);
}

typedef __attribute__((address_space(1))) const unsigned int guint;
typedef __attribute__((address_space(3))) unsigned int luint;
__device__ __forceinline__ void gload_lds16(const void* g, void* l) {
    __builtin_amdgcn_global_load_lds((guint*)g, (luint*)l, 16, 0, 0);
}

using bfrag = __attribute__((ext_vector_type(8))) short;   // 8 bf16 = 4 VGPR
using f4    = __attribute__((ext_vector_type(4))) float;

// ---------- weight fp32 -> bf16 conversion (7 tensors in one launch) ----------
struct CvtArgs {
    const float* src[7];
    ushort*      dst[7];
    int          n[7];
};
__global__ __launch_bounds__(256) void cvt_kernel(CvtArgs a) {
    int t = blockIdx.y;
    int i = (blockIdx.x * 256 + threadIdx.x) * 4;
    if (i < a.n[t]) {
        float4 v = *(const float4*)&a.src[t][i];
        ushort4 o;
        o.x = f2bf(v.x); o.y = f2bf(v.y); o.z = f2bf(v.z); o.w = f2bf(v.w);
        *(ushort4*)&a.dst[t][i] = o;
    }
}

// ---------- zero fp32 buffer (float4 granularity) ----------
__global__ __launch_bounds__(256) void zero_kernel(float* __restrict__ p, int n4) {
    int i = blockIdx.x * 256 + threadIdx.x;
    if (i < n4) ((float4*)p)[i] = float4{0.f, 0.f, 0.f, 0.f};
}

// ---------- xs = bf16(x + up2(prev)) (prev may be null) ----------
__global__ __launch_bounds__(256) void xs_kernel(
    const float* __restrict__ x, const float* __restrict__ prev,
    ushort* __restrict__ xs, int BC, int H, int W)
{
    int idx = blockIdx.x * 256 + threadIdx.x;       // over BC*H*(W/2)
    int W2 = W >> 1;
    int total = BC * H * W2;
    if (idx >= total) return;
    int wp = idx % W2;
    int rest = idx / W2;
    int h = rest % H, bc = rest / H;
    float2 xv = *(const float2*)&x[((size_t)bc * H + h) * W + wp * 2];
    float tv = prev ? prev[((size_t)bc * (H >> 1) + (h >> 1)) * W2 + wp] : 0.f;
    unsigned int pack = (unsigned int)f2bf(xv.x + tv) |
                        ((unsigned int)f2bf(xv.y + tv) << 16);
    ((unsigned int*)xs)[idx] = pack;
}

// ---------- offset conv: bf16 MFMA, M=27 (padded 32), split-K, atomic fp32 ----------
// A: owbf [27][K], xs: [B][C][H][W] bf16, offbuf: [B][27][N] fp32 (pre-zeroed)
// grid: (ceil(N/64), 72/ktiles, B), block 256.
__global__ __launch_bounds__(256) void off_mfma(
    const ushort* __restrict__ A, const ushort* __restrict__ xs,
    float* __restrict__ offbuf,
    int N, int K, int H, int W, int C, int ktiles)
{
    __shared__ __align__(16) ushort As[32 * 32];
    __shared__ __align__(16) ushort Bs[64 * 32];
    const int b  = blockIdx.z;
    const int n0 = blockIdx.x * 64;
    const int kt0 = blockIdx.y * ktiles * 32;
    const int tid = threadIdx.x, lane = tid & 63, wv = tid >> 6;
    const ushort* xb = xs + (size_t)b * C * H * W;

    f4 acc[2] = {};

    for (int kk = 0; kk < ktiles; ++kk) {
        int kt = kt0 + kk * 32;
        // A tile: 32 rows x 32 k = 128 x 16B chunks, waves 0-1
        if (tid < 128) {
            int row = tid >> 2; if (row > 26) row = 26;   // pad rows load row 26
            int kc = (tid & 3) * 8;
            gload_lds16(A + (size_t)row * K + kt + kc,
                        (char*)As + (size_t)(tid & ~63) * 16);
        }
        // B tile: 64 n x 32 k, implicit im2col gather from xs
        {
            int row = tid >> 2, kc = (tid & 3) * 8;
            int n = n0 + row; if (n >= N) n = N - 1;
            int h = n / W, w = n - h * W;
            ushort vals[8];
            #pragma unroll
            for (int t = 0; t < 8; ++t) {
                int q = kt + kc + t;
                int c = q / 9, r = q - c * 9;
                int ih = h + r / 3 - 1, iw = w + (r % 3) - 1;
                ushort v = 0;
                if (ih >= 0 && ih < H && iw >= 0 && iw < W)
                    v = xb[((size_t)c * H + ih) * W + iw];
                vals[t] = v;
            }
            *(uint4*)((char*)Bs + (size_t)tid * 16) = *(uint4*)vals;
        }
        __syncthreads();
        bfrag bf = *(const bfrag*)&Bs[(wv * 16 + (lane & 15)) * 32 + (lane >> 4) * 8];
        bfrag a0 = *(const bfrag*)&As[(lane & 15) * 32 + (lane >> 4) * 8];
        bfrag a1 = *(const bfrag*)&As[(16 + (lane & 15)) * 32 + (lane >> 4) * 8];
        acc[0] = __builtin_amdgcn_mfma_f32_16x16x32_bf16(a0, bf, acc[0], 0, 0, 0);
        acc[1] = __builtin_amdgcn_mfma_f32_16x16x32_bf16(a1, bf, acc[1], 0, 0, 0);
        __syncthreads();
    }

    int n = n0 + wv * 16 + (lane & 15);
    if (n < N) {
        #pragma unroll
        for (int mb = 0; mb < 2; ++mb)
            #pragma unroll
            for (int t = 0; t < 4; ++t) {
                int m = mb * 16 + (lane >> 4) * 4 + t;
                if (m < 27)
                    atomicAdd(&offbuf[((size_t)b * 27 + m) * N + n], acc[mb][t]);
            }
    }
}

// ---------- deformable sampling from xs (bf16) -> cols[b][n][q] bf16 ----------
// grid: (ceil(HW/256), C/32, B), block 256 (one thread per hw)
__global__ __launch_bounds__(256) void sampling_kernel(
    const ushort* __restrict__ xs, const float* __restrict__ off,
    const float* __restrict__ ob, ushort* __restrict__ cols,
    int C, int H, int W)
{
    const int HW = H * W;
    const size_t Kk = (size_t)C * 9;
    int b = blockIdx.z;
    int c0 = blockIdx.y * 32;
    int hw = blockIdx.x * 256 + threadIdx.x;
    bool active = hw < HW;
    if (!active) hw = HW - 1;
    int h = hw / W, w = hw - h * W;

    const float* offb = off + (size_t)b * 27 * HW;
    float w00[9], w01[9], w10[9], w11[9];
    int o00[9], o01[9], o10[9], o11[9];
    #pragma unroll
    for (int k = 0; k < 9; ++k) {
        float dy = offb[(size_t)(2 * k) * HW + hw] + ob[2 * k];
        float dx = offb[(size_t)(2 * k + 1) * HW + hw] + ob[2 * k + 1];
        float mv = offb[(size_t)(18 + k) * HW + hw] + ob[18 + k];
        float mk = 1.0f / (1.0f + __expf(-mv));
        float py = (float)h - 1.0f + (float)(k / 3) + dy;
        float px = (float)w - 1.0f + (float)(k % 3) + dx;
        float y0f = floorf(py), x0f = floorf(px);
        float wy = py - y0f, wx = px - x0f;
        int y0 = (int)y0f, x0i = (int)x0f;
        int y1 = y0 + 1, x1 = x0i + 1;
        bool vy0 = (y0 >= 0) & (y0 < H), vy1 = (y1 >= 0) & (y1 < H);
        bool vx0 = (x0i >= 0) & (x0i < W), vx1 = (x1 >= 0) & (x1 < W);
        w00[k] = (1.f - wy) * (1.f - wx) * ((vy0 & vx0) ? mk : 0.f);
        w01[k] = (1.f - wy) * wx        * ((vy0 & vx1) ? mk : 0.f);
        w10[k] = wy * (1.f - wx)        * ((vy1 & vx0) ? mk : 0.f);
        w11[k] = wy * wx                * ((vy1 & vx1) ? mk : 0.f);
        int cy0 = min(max(y0, 0), H - 1), cy1 = min(max(y1, 0), H - 1);
        int cx0 = min(max(x0i, 0), W - 1), cx1 = min(max(x1, 0), W - 1);
        o00[k] = cy0 * W + cx0; o01[k] = cy0 * W + cx1;
        o10[k] = cy1 * W + cx0; o11[k] = cy1 * W + cx1;
    }

    const ushort* xp = xs + ((size_t)b * C + c0) * HW;
    ushort* colp = cols + ((size_t)b * HW + hw) * Kk + (size_t)c0 * 9;

    for (int cc = 0; cc < 32; cc += 8) {
        ushort buf[72];
        #pragma unroll
        for (int c8 = 0; c8 < 8; ++c8) {
            const ushort* xc = xp + (size_t)(cc + c8) * HW;
            #pragma unroll
            for (int k = 0; k < 9; ++k) {
                float g00 = bf2f(xc[o00[k]]);
                float g01 = bf2f(xc[o01[k]]);
                float g10 = bf2f(xc[o10[k]]);
                float g11 = bf2f(xc[o11[k]]);
                buf[c8 * 9 + k] = f2bf(g00 * w00[k] + g01 * w01[k] +
                                       g10 * w10[k] + g11 * w11[k]);
            }
        }
        if (active) {
            uint4* dst = (uint4*)(colp + (size_t)cc * 9);  // 144 B, 16B-aligned
            #pragma unroll
            for (int t = 0; t < 9; ++t) dst[t] = ((uint4*)buf)[t];
        }
    }
}

// ---------- bf16 MFMA GEMM (m97-style, TN: A[M][K], Bt[N][K]) ----------
// IMPLICIT: Bt is xs bf16 [b][C][H][W], B-operand built by im2col in staging.
template<bool IMPLICIT>
__global__ __launch_bounds__(256) void mfma_gemm(
    const ushort* __restrict__ A, const float* __restrict__ bias,
    const ushort* __restrict__ Bt, float* __restrict__ outp,
    int M, int N, int K, int H, int W)
{
    __shared__ __align__(16) ushort As[128 * 32];
    __shared__ __align__(16) ushort Bs[128 * 32];
    const int b  = blockIdx.z;
    const int m0 = blockIdx.y * 128;
    const int n0 = blockIdx.x * 128;
    const int tid  = threadIdx.x;
    const int lane = tid & 63;
    const int wv   = tid >> 6;
    const int wm = wv >> 1, wn = wv & 1;
    const int C = K / 9;

    f4 acc[4][4] = {};

    const ushort* Bb = IMPLICIT ? Bt + (size_t)b * C * H * W
                                : Bt + (size_t)b * (size_t)N * K;

    for (int kt = 0; kt < K; kt += 32) {
        #pragma unroll
        for (int j = 0; j < 2; ++j) {
            int i = j * 256 + tid;
            int row = i >> 2, kc = (i & 3) * 8;
            const ushort* g = A + (size_t)(m0 + row) * K + kt + kc;
            gload_lds16(g, (char*)As + (size_t)(j * 256 + (tid & ~63)) * 16);
        }
        if (!IMPLICIT) {
            #pragma unroll
            for (int j = 0; j < 2; ++j) {
                int i = j * 256 + tid;
                int row = i >> 2, kc = (i & 3) * 8;
                int n = n0 + row; if (n >= N) n = N - 1;
                const ushort* g = Bb + (size_t)n * K + kt + kc;
                gload_lds16(g, (char*)Bs + (size_t)(j * 256 + (tid & ~63)) * 16);
            }
        } else {
            #pragma unroll
            for (int j = 0; j < 2; ++j) {
                int ci = j * 256 + tid;
                int row = ci >> 2, kc = (ci & 3) * 8;
                int n = n0 + row; if (n >= N) n = N - 1;
                int h = n / W, w = n % W;
                ushort vals[8];
                #pragma unroll
                for (int t = 0; t < 8; ++t) {
                    int q = kt + kc + t;
                    int c = q / 9, r = q - c * 9;
                    int ih = h + r / 3 - 1, iw = w + r % 3 - 1;
                    ushort v = 0;
                    if (ih >= 0 && ih < H && iw >= 0 && iw < W)
                        v = Bb[((size_t)c * H + ih) * W + iw];
                    vals[t] = v;
                }
                *(uint4*)((char*)Bs + (size_t)ci * 16) = *(uint4*)vals;
            }
        }
        __syncthreads();

        bfrag af[4], bf[4];
        #pragma unroll
        for (int i = 0; i < 4; ++i)
            af[i] = *(const bfrag*)&As[(wm * 64 + i * 16 + (lane & 15)) * 32 + (lane >> 4) * 8];
        #pragma unroll
        for (int j = 0; j < 4; ++j)
            bf[j] = *(const bfrag*)&Bs[(wn * 64 + j * 16 + (lane & 15)) * 32 + (lane >> 4) * 8];
        #pragma unroll
        for (int i = 0; i < 4; ++i)
            #pragma unroll
            for (int j = 0; j < 4; ++j)
                acc[i][j] = __builtin_amdgcn_mfma_f32_16x16x32_bf16(af[i], bf[j], acc[i][j], 0, 0, 0);
        __syncthreads();
    }

    const int mb = m0 + wm * 64, nb = n0 + wn * 64;
    #pragma unroll
    for (int i = 0; i < 4; ++i) {
        int mrow = mb + i * 16 + (lane >> 4) * 4;
        #pragma unroll
        for (int j = 0; j < 4; ++j) {
            int n = nb + j * 16 + (lane & 15);
            if (n < N) {
                #pragma unroll
                for (int t = 0; t < 4; ++t) {
                    int m = mrow + t;
                    outp[((size_t)b * M + m) * (size_t)N + n] = acc[i][j][t] + bias[m];
                }
            }
        }
    }
}

// ---------- host launch ----------
extern "C" void kernel_launch(void* const* d_in, const int* in_sizes, int n_in,
                              void* d_out, int out_size, void* d_ws, size_t ws_size,
                              hipStream_t stream)
{
    const float* x[4]   = {(const float*)d_in[0], (const float*)d_in[1],
                           (const float*)d_in[2], (const float*)d_in[3]};
    const float* wgt[4] = {(const float*)d_in[4], (const float*)d_in[6],
                           (const float*)d_in[8], (const float*)d_in[10]};
    const float* bia[4] = {(const float*)d_in[5], (const float*)d_in[7],
                           (const float*)d_in[9], (const float*)d_in[11]};
    const float* owt[4] = {nullptr, (const float*)d_in[12],
                           (const float*)d_in[14], (const float*)d_in[16]};
    const float* obv[4] = {nullptr, (const float*)d_in[13],
                           (const float*)d_in[15], (const float*)d_in[17]};

    const int B = 2, C = 256, K = 2304;
    const int Hs[4] = {96, 48, 24, 12};
    const int HWs[4] = {96 * 96, 48 * 48, 24 * 24, 12 * 12};

    float* out = (float*)d_out;
    size_t outOff[4];
    outOff[0] = 0;
    outOff[1] = outOff[0] + (size_t)B * C * HWs[0];
    outOff[2] = outOff[1] + (size_t)B * C * HWs[1];
    outOff[3] = outOff[2] + (size_t)B * C * HWs[2];

    // ---- ws carve (256B aligned)
    char* ws = (char*)d_ws;
    size_t off = 0;
    auto carve = [&](size_t bytes) { void* p = ws + off; off = (off + bytes + 255) & ~(size_t)255; return p; };
    ushort* wbf[4];
    ushort* owbf[4] = {nullptr, nullptr, nullptr, nullptr};
    const int WN = 256 * K, OWN = 27 * K;
    for (int i = 0; i < 4; ++i) wbf[i] = (ushort*)carve((size_t)WN * 2);
    for (int i = 1; i < 4; ++i) owbf[i] = (ushort*)carve((size_t)OWN * 2);
    ushort* cols = (ushort*)carve((size_t)B * HWs[1] * K * 2);     // max: level 1
    ushort* xsb[4];
    for (int i = 0; i < 4; ++i) xsb[i] = (ushort*)carve((size_t)B * C * HWs[i] * 2);
    // offbufs contiguous fp32: lvl1 | lvl2 | lvl3
    int offElems = B * 27 * (HWs[1] + HWs[2] + HWs[3]);
    float* offbase = (float*)carve((size_t)offElems * 4);
    float* offbuf[4] = {nullptr,
                        offbase,
                        offbase + (size_t)B * 27 * HWs[1],
                        offbase + (size_t)B * 27 * (HWs[1] + HWs[2])};

    // ---- upfront: weight cvt, offbuf zero, xs3
    {
        CvtArgs a;
        a.src[0] = wgt[0]; a.src[1] = wgt[1]; a.src[2] = wgt[2]; a.src[3] = wgt[3];
        a.src[4] = owt[1]; a.src[5] = owt[2]; a.src[6] = owt[3];
        a.dst[0] = wbf[0]; a.dst[1] = wbf[1]; a.dst[2] = wbf[2]; a.dst[3] = wbf[3];
        a.dst[4] = owbf[1]; a.dst[5] = owbf[2]; a.dst[6] = owbf[3];
        for (int i = 0; i < 4; ++i) a.n[i] = WN;
        for (int i = 4; i < 7; ++i) a.n[i] = OWN;
        dim3 grd((WN / 4 + 255) / 256, 7);
        cvt_kernel<<<grd, 256, 0, stream>>>(a);
    }
    {
        int n4 = offElems / 4;
        zero_kernel<<<(n4 + 255) / 256, 256, 0, stream>>>(offbase, n4);
    }
    {
        int total = B * C * Hs[3] * (Hs[3] / 2);
        xs_kernel<<<(total + 255) / 256, 256, 0, stream>>>(
            x[3], nullptr, xsb[3], B * C, Hs[3], Hs[3]);
    }

    const int ktiles[4] = {0, 9, 6, 3};   // K-chunk = ktiles*32; 72/ktiles chunks

    for (int lvl = 3; lvl >= 1; --lvl) {
        int H = Hs[lvl], W = H, HW = HWs[lvl];

        // offset conv: bf16 MFMA split-K
        {
            dim3 grd((HW + 63) / 64, 72 / ktiles[lvl], B);
            off_mfma<<<grd, 256, 0, stream>>>(
                owbf[lvl], xsb[lvl], offbuf[lvl], HW, K, H, W, C, ktiles[lvl]);
        }
        // deformable sampling -> cols [b][n][q] bf16 (bias folded here)
        {
            dim3 grd((HW + 255) / 256, C / 32, B);
            sampling_kernel<<<grd, 256, 0, stream>>>(
                xsb[lvl], offbuf[lvl], obv[lvl], cols, C, H, W);
        }
        // main conv: bf16 MFMA GEMM, explicit cols
        {
            dim3 grd((HW + 127) / 128, 2, B);
            mfma_gemm<false><<<grd, 256, 0, stream>>>(
                wbf[lvl], bia[lvl], cols, out + outOff[lvl],
                256, HW, K, H, W);
        }
        // xs for next-finer level (needs t_lvl just computed)
        {
            int Hn = Hs[lvl - 1];
            int total = B * C * Hn * (Hn / 2);
            xs_kernel<<<(total + 255) / 256, 256, 0, stream>>>(
                x[lvl - 1], out + outOff[lvl], xsb[lvl - 1], B * C, Hn, Hn);
        }
    }

    // level 0: implicit-im2col MFMA GEMM on xs0
    {
        int H = 96, W = 96, HW = HWs[0];
        dim3 grd((HW + 127) / 128, 2, B);
        mfma_gemm<true><<<grd, 256, 0, stream>>>(
            wbf[0], bia[0], xsb[0], out + outOff[0],
            256, HW, K, H, W);
    }
}

// Round 4
// 324.316 us; speedup vs baseline: 8.7293x; 1.8983x over previous
//
#include <hip/hip_runtime.h>
#include <math.h>

// ---------- helpers ----------
__device__ __forceinline__ ushort f2bf(float f) {
    unsigned int u = __float_as_uint(f);
    u += 0x7FFFu + ((u >> 16) & 1u);   // round-to-nearest-even
    return (ushort)(u >> 16);
}
__device__ __forceinline__ float bf2f(ushort u) {
    return __uint_as_float((unsigned int)u << 16);
}

typedef __attribute__((address_space(1))) const unsigned int guint;
typedef __attribute__((address_space(3))) unsigned int luint;
__device__ __forceinline__ void gload_lds16(const void* g, void* l) {
    __builtin_amdgcn_global_load_lds((guint*)g, (luint*)l, 16, 0, 0);
}

using bfrag = __attribute__((ext_vector_type(8))) short;   // 8 bf16 = 4 VGPR
using f4    = __attribute__((ext_vector_type(4))) float;

__device__ __forceinline__ void bf8_to_f(uint4 v, float* o) {
    unsigned int u[4] = {v.x, v.y, v.z, v.w};
    #pragma unroll
    for (int i = 0; i < 4; ++i) {
        o[2 * i]     = __uint_as_float(u[i] << 16);
        o[2 * i + 1] = __uint_as_float(u[i] & 0xFFFF0000u);
    }
}

// ---------- weight cvt + reorder: w[m][c][r] fp32 -> wq[m][r*256+c] bf16 ----------
struct CvtArgs {
    const float* src[7];
    ushort*      dst[7];
    int          m[7];      // rows (256 or 27)
};
__global__ __launch_bounds__(256) void cvt_kernel(CvtArgs a) {
    int t = blockIdx.y;
    int idx = blockIdx.x * 256 + threadIdx.x;    // m*288 + r*32 + c8
    int M = a.m[t];
    if (idx >= M * 288) return;
    int m = idx / 288, rem = idx - m * 288;
    int r = rem >> 5, c8 = rem & 31;
    const float* s = a.src[t] + ((size_t)(m * 256 + c8 * 8)) * 9 + r;
    ushort vals[8];
    #pragma unroll
    for (int j = 0; j < 8; ++j) vals[j] = f2bf(s[j * 9]);
    *(uint4*)&a.dst[t][(size_t)m * 2304 + r * 256 + c8 * 8] = *(uint4*)vals;
}

// ---------- zero fp32/raw buffer (16B granularity) ----------
__global__ __launch_bounds__(256) void zero_kernel(float* __restrict__ p, int n4) {
    int i = blockIdx.x * 256 + threadIdx.x;
    if (i < n4) ((float4*)p)[i] = float4{0.f, 0.f, 0.f, 0.f};
}

// ---------- xs = NHWC bf16 of (x + up2(prev)); x,prev NCHW fp32 ----------
// grid: (ceil(HW/64), 256/32, B), block 256
__global__ __launch_bounds__(256) void xs_nhwc(
    const float* __restrict__ x, const float* __restrict__ prev,
    ushort* __restrict__ xs, int H, int W)
{
    __shared__ ushort tile[32][72];
    const int HW = H * W, W2 = W >> 1;
    int b = blockIdx.z, c0 = blockIdx.y * 32, hw0 = blockIdx.x * 64;
    const float* xb = x + ((size_t)b * 256 + c0) * HW;
    const float* pb = prev ? prev + ((size_t)b * 256 + c0) * (HW >> 2) : nullptr;

    int hwl = threadIdx.x & 63, cl0 = threadIdx.x >> 6;
    int hw = hw0 + hwl;
    bool ok = hw < HW;
    int hwc = ok ? hw : HW - 1;
    int h = hwc / W, w = hwc - h * W;
    int pidx = (h >> 1) * W2 + (w >> 1);
    #pragma unroll
    for (int p = 0; p < 8; ++p) {
        int cl = p * 4 + cl0;
        float v = 0.f;
        if (ok) {
            v = xb[(size_t)cl * HW + hw];
            if (pb) v += pb[(size_t)cl * (HW >> 2) + pidx];
        }
        tile[cl][hwl] = f2bf(v);
    }
    __syncthreads();
    int hwl2 = threadIdx.x >> 2, cc = (threadIdx.x & 3) * 8;
    int hw2 = hw0 + hwl2;
    if (hw2 < HW) {
        ushort vals[8];
        #pragma unroll
        for (int j = 0; j < 8; ++j) vals[j] = tile[cc + j][hwl2];
        *(uint4*)&xs[((size_t)b * HW + hw2) * 256 + c0 + cc] = *(uint4*)vals;
    }
}

// ---------- offset conv: bf16 MFMA, M=27 (pad 32), split-K, NHWC implicit ----------
// grid: (ceil(N/64), 72/ktiles, B)
__global__ __launch_bounds__(256) void off_mfma(
    const ushort* __restrict__ A, const ushort* __restrict__ xs,
    const ushort* __restrict__ zeros, float* __restrict__ offbuf,
    int N, int H, int W, int ktiles)
{
    __shared__ __align__(16) ushort As[32 * 32];
    __shared__ __align__(16) ushort Bs[64 * 32];
    const int b  = blockIdx.z;
    const int n0 = blockIdx.x * 64;
    const int kt0 = blockIdx.y * ktiles * 32;
    const int tid = threadIdx.x, lane = tid & 63, wv = tid >> 6;
    const ushort* xb = xs + (size_t)b * N * 256;

    int n = n0 + (tid >> 2); if (n >= N) n = N - 1;
    int h = n / W, w = n - h * W;
    int kcc = (tid & 3) * 8;

    f4 acc[2] = {};

    for (int kk = 0; kk < ktiles; ++kk) {
        int kt = kt0 + kk * 32;
        int r = kt >> 8, c0k = kt & 255;
        int ry = r / 3 - 1, rx = r - (r / 3) * 3 - 1;
        if (tid < 128) {
            int row = tid >> 2; if (row > 26) row = 26;
            gload_lds16(A + (size_t)row * 2304 + kt + kcc,
                        (char*)As + (size_t)(tid & ~63) * 16);
        }
        {
            int ih = h + ry, iw = w + rx;
            const ushort* src = (ih >= 0 && ih < H && iw >= 0 && iw < W)
                ? xb + (((size_t)(ih * W + iw)) << 8) + c0k + kcc
                : zeros;
            gload_lds16(src, (char*)Bs + (size_t)(tid & ~63) * 16);
        }
        __syncthreads();
        bfrag bf = *(const bfrag*)&Bs[(wv * 16 + (lane & 15)) * 32 + (lane >> 4) * 8];
        bfrag a0 = *(const bfrag*)&As[(lane & 15) * 32 + (lane >> 4) * 8];
        bfrag a1 = *(const bfrag*)&As[(16 + (lane & 15)) * 32 + (lane >> 4) * 8];
        acc[0] = __builtin_amdgcn_mfma_f32_16x16x32_bf16(a0, bf, acc[0], 0, 0, 0);
        acc[1] = __builtin_amdgcn_mfma_f32_16x16x32_bf16(a1, bf, acc[1], 0, 0, 0);
        __syncthreads();
    }

    int nn = n0 + wv * 16 + (lane & 15);
    if (nn < N) {
        #pragma unroll
        for (int mb = 0; mb < 2; ++mb)
            #pragma unroll
            for (int t = 0; t < 4; ++t) {
                int m = mb * 16 + (lane >> 4) * 4 + t;
                if (m < 27)
                    atomicAdd(&offbuf[((size_t)b * 27 + m) * N + nn], acc[mb][t]);
            }
    }
}

// ---------- deformable sampling (NHWC) -> cols[b][hw][r*256+c] bf16 ----------
// grid: (ceil(HW*8/256), 1, B); thread = (hw, c-block of 32)
__global__ __launch_bounds__(256) void sampling_kernel(
    const ushort* __restrict__ xs, const float* __restrict__ off,
    const float* __restrict__ ob, ushort* __restrict__ cols,
    int H, int W)
{
    const int HW = H * W;
    int idx = blockIdx.x * 256 + threadIdx.x;
    if (idx >= HW * 8) return;
    int b = blockIdx.z;
    int hw = idx >> 3, cb = (idx & 7) * 32;
    int h = hw / W, w = hw - h * W;

    const float* offb = off + (size_t)b * 27 * HW;
    const ushort* xb = xs + (size_t)b * HW * 256;
    ushort* colp = cols + ((size_t)b * HW + hw) * 2304 + cb;

    #pragma unroll
    for (int k = 0; k < 9; ++k) {
        float dy = offb[(size_t)(2 * k) * HW + hw] + ob[2 * k];
        float dx = offb[(size_t)(2 * k + 1) * HW + hw] + ob[2 * k + 1];
        float mv = offb[(size_t)(18 + k) * HW + hw] + ob[18 + k];
        float mk = 1.0f / (1.0f + __expf(-mv));
        float py = (float)h - 1.0f + (float)(k / 3) + dy;
        float px = (float)w - 1.0f + (float)(k % 3) + dx;
        float y0f = floorf(py), x0f = floorf(px);
        float wy = py - y0f, wx = px - x0f;
        int y0 = (int)y0f, x0i = (int)x0f;
        int y1 = y0 + 1, x1 = x0i + 1;
        bool vy0 = (y0 >= 0) & (y0 < H), vy1 = (y1 >= 0) & (y1 < H);
        bool vx0 = (x0i >= 0) & (x0i < W), vx1 = (x1 >= 0) & (x1 < W);
        float w00 = (1.f - wy) * (1.f - wx) * ((vy0 & vx0) ? mk : 0.f);
        float w01 = (1.f - wy) * wx        * ((vy0 & vx1) ? mk : 0.f);
        float w10 = wy * (1.f - wx)        * ((vy1 & vx0) ? mk : 0.f);
        float w11 = wy * wx                * ((vy1 & vx1) ? mk : 0.f);
        int cy0 = min(max(y0, 0), H - 1), cy1 = min(max(y1, 0), H - 1);
        int cx0 = min(max(x0i, 0), W - 1), cx1 = min(max(x1, 0), W - 1);
        const ushort* p00 = xb + (((size_t)(cy0 * W + cx0)) << 8) + cb;
        const ushort* p01 = xb + (((size_t)(cy0 * W + cx1)) << 8) + cb;
        const ushort* p10 = xb + (((size_t)(cy1 * W + cx0)) << 8) + cb;
        const ushort* p11 = xb + (((size_t)(cy1 * W + cx1)) << 8) + cb;

        #pragma unroll
        for (int j = 0; j < 4; ++j) {
            float f00[8], f01[8], f10[8], f11[8];
            bf8_to_f(*(const uint4*)(p00 + 8 * j), f00);
            bf8_to_f(*(const uint4*)(p01 + 8 * j), f01);
            bf8_to_f(*(const uint4*)(p10 + 8 * j), f10);
            bf8_to_f(*(const uint4*)(p11 + 8 * j), f11);
            unsigned int pk[4];
            #pragma unroll
            for (int t = 0; t < 4; ++t) {
                float lo = f00[2 * t] * w00 + f01[2 * t] * w01 +
                           f10[2 * t] * w10 + f11[2 * t] * w11;
                float hi = f00[2 * t + 1] * w00 + f01[2 * t + 1] * w01 +
                           f10[2 * t + 1] * w10 + f11[2 * t + 1] * w11;
                pk[t] = (unsigned int)f2bf(lo) | ((unsigned int)f2bf(hi) << 16);
            }
            *(uint4*)(colp + k * 256 + 8 * j) = make_uint4(pk[0], pk[1], pk[2], pk[3]);
        }
    }
}

// ---------- bias prefill for split-K outputs ----------
__global__ __launch_bounds__(256) void bias_fill(
    float* __restrict__ outp, const float* __restrict__ bias, int N)
{
    int m = blockIdx.y, b = blockIdx.z;
    int n = blockIdx.x * 256 + threadIdx.x;
    if (n < N) outp[((size_t)b * 256 + m) * N + n] = bias[m];
}

// ---------- bf16 MFMA GEMM: A[M=256][K], B = cols[N][K] or NHWC implicit ----------
// grid: (ceil(N/128), 2*S, B); kchunk = K/S
template<bool IMPLICIT, bool SPLITK>
__global__ __launch_bounds__(256) void mfma_gemm(
    const ushort* __restrict__ A, const float* __restrict__ bias,
    const ushort* __restrict__ Bt, const ushort* __restrict__ zeros,
    float* __restrict__ outp, int N, int H, int W, int kchunk)
{
    __shared__ __align__(16) ushort As[128 * 32];
    __shared__ __align__(16) ushort Bs[128 * 32];
    const int b  = blockIdx.z;
    const int m0 = (blockIdx.y & 1) * 128;
    const int kt0 = (blockIdx.y >> 1) * kchunk;
    const int n0 = blockIdx.x * 128;
    const int tid  = threadIdx.x;
    const int lane = tid & 63;
    const int wv   = tid >> 6;
    const int wm = wv >> 1, wn = wv & 1;
    const int kcc = (tid & 3) * 8;

    f4 acc[4][4] = {};

    const ushort* Bb = IMPLICIT ? Bt + (size_t)b * N * 256
                                : Bt + (size_t)b * (size_t)N * 2304;

    // per-thread implicit-gemm pixel coords (row j covers n0 + j*64 + tid/4)
    int hh[2], ww[2];
    if (IMPLICIT) {
        #pragma unroll
        for (int j = 0; j < 2; ++j) {
            int n = n0 + j * 64 + (tid >> 2); if (n >= N) n = N - 1;
            hh[j] = n / W; ww[j] = n - hh[j] * W;
        }
    }

    const int kend = kt0 + kchunk;
    for (int kt = kt0; kt < kend; kt += 32) {
        #pragma unroll
        for (int j = 0; j < 2; ++j) {
            int row = j * 64 + (tid >> 2);
            gload_lds16(A + (size_t)(m0 + row) * 2304 + kt + kcc,
                        (char*)As + (size_t)(j * 256 + (tid & ~63)) * 16);
        }
        if (!IMPLICIT) {
            #pragma unroll
            for (int j = 0; j < 2; ++j) {
                int n = n0 + j * 64 + (tid >> 2); if (n >= N) n = N - 1;
                gload_lds16(Bb + (size_t)n * 2304 + kt + kcc,
                            (char*)Bs + (size_t)(j * 256 + (tid & ~63)) * 16);
            }
        } else {
            int r = kt >> 8, c0k = kt & 255;
            int ry = r / 3 - 1, rx = r - (r / 3) * 3 - 1;
            #pragma unroll
            for (int j = 0; j < 2; ++j) {
                int ih = hh[j] + ry, iw = ww[j] + rx;
                const ushort* src = (ih >= 0 && ih < H && iw >= 0 && iw < W)
                    ? Bb + (((size_t)(ih * W + iw)) << 8) + c0k + kcc
                    : zeros;
                gload_lds16(src, (char*)Bs + (size_t)(j * 256 + (tid & ~63)) * 16);
            }
        }
        __syncthreads();

        bfrag af[4], bf[4];
        #pragma unroll
        for (int i = 0; i < 4; ++i)
            af[i] = *(const bfrag*)&As[(wm * 64 + i * 16 + (lane & 15)) * 32 + (lane >> 4) * 8];
        #pragma unroll
        for (int j = 0; j < 4; ++j)
            bf[j] = *(const bfrag*)&Bs[(wn * 64 + j * 16 + (lane & 15)) * 32 + (lane >> 4) * 8];
        #pragma unroll
        for (int i = 0; i < 4; ++i)
            #pragma unroll
            for (int j = 0; j < 4; ++j)
                acc[i][j] = __builtin_amdgcn_mfma_f32_16x16x32_bf16(af[i], bf[j], acc[i][j], 0, 0, 0);
        __syncthreads();
    }

    const int mb = m0 + wm * 64, nb = n0 + wn * 64;
    #pragma unroll
    for (int i = 0; i < 4; ++i) {
        int mrow = mb + i * 16 + (lane >> 4) * 4;
        #pragma unroll
        for (int j = 0; j < 4; ++j) {
            int n = nb + j * 16 + (lane & 15);
            if (n < N) {
                #pragma unroll
                for (int t = 0; t < 4; ++t) {
                    int m = mrow + t;
                    if (SPLITK)
                        atomicAdd(&outp[((size_t)b * 256 + m) * N + n], acc[i][j][t]);
                    else
                        outp[((size_t)b * 256 + m) * N + n] = acc[i][j][t] + bias[m];
                }
            }
        }
    }
}

// ---------- host launch ----------
extern "C" void kernel_launch(void* const* d_in, const int* in_sizes, int n_in,
                              void* d_out, int out_size, void* d_ws, size_t ws_size,
                              hipStream_t stream)
{
    const float* x[4]   = {(const float*)d_in[0], (const float*)d_in[1],
                           (const float*)d_in[2], (const float*)d_in[3]};
    const float* wgt[4] = {(const float*)d_in[4], (const float*)d_in[6],
                           (const float*)d_in[8], (const float*)d_in[10]};
    const float* bia[4] = {(const float*)d_in[5], (const float*)d_in[7],
                           (const float*)d_in[9], (const float*)d_in[11]};
    const float* owt[4] = {nullptr, (const float*)d_in[12],
                           (const float*)d_in[14], (const float*)d_in[16]};
    const float* obv[4] = {nullptr, (const float*)d_in[13],
                           (const float*)d_in[15], (const float*)d_in[17]};

    const int B = 2;
    const int Hs[4] = {96, 48, 24, 12};
    const int HWs[4] = {96 * 96, 48 * 48, 24 * 24, 12 * 12};

    float* out = (float*)d_out;
    size_t outOff[4];
    outOff[0] = 0;
    outOff[1] = outOff[0] + (size_t)B * 256 * HWs[0];
    outOff[2] = outOff[1] + (size_t)B * 256 * HWs[1];
    outOff[3] = outOff[2] + (size_t)B * 256 * HWs[2];

    // ---- ws carve (256B aligned)
    char* ws = (char*)d_ws;
    size_t off = 0;
    auto carve = [&](size_t bytes) { void* p = ws + off; off = (off + bytes + 255) & ~(size_t)255; return p; };
    ushort* wbf[4];
    ushort* owbf[4] = {nullptr, nullptr, nullptr, nullptr};
    for (int i = 0; i < 4; ++i) wbf[i] = (ushort*)carve((size_t)256 * 2304 * 2);
    for (int i = 1; i < 4; ++i) owbf[i] = (ushort*)carve((size_t)27 * 2304 * 2);
    ushort* cols = (ushort*)carve((size_t)B * HWs[1] * 2304 * 2);   // max: level 1
    ushort* xsb[4];
    for (int i = 0; i < 4; ++i) xsb[i] = (ushort*)carve((size_t)B * 256 * HWs[i] * 2);
    int offElems = B * 27 * (HWs[1] + HWs[2] + HWs[3]);
    float* offbase = (float*)carve((size_t)offElems * 4 + 1024);
    ushort* zeros = (ushort*)(offbase + offElems);   // 1 KB zero page
    float* offbuf[4] = {nullptr,
                        offbase,
                        offbase + (size_t)B * 27 * HWs[1],
                        offbase + (size_t)B * 27 * (HWs[1] + HWs[2])};

    // ---- upfront: weight cvt+reorder, zero (offbuf + zero page), xs3
    {
        CvtArgs a;
        a.src[0] = wgt[0]; a.src[1] = wgt[1]; a.src[2] = wgt[2]; a.src[3] = wgt[3];
        a.src[4] = owt[1]; a.src[5] = owt[2]; a.src[6] = owt[3];
        a.dst[0] = wbf[0]; a.dst[1] = wbf[1]; a.dst[2] = wbf[2]; a.dst[3] = wbf[3];
        a.dst[4] = owbf[1]; a.dst[5] = owbf[2]; a.dst[6] = owbf[3];
        for (int i = 0; i < 4; ++i) a.m[i] = 256;
        for (int i = 4; i < 7; ++i) a.m[i] = 27;
        dim3 grd((256 * 288 + 255) / 256, 7);
        cvt_kernel<<<grd, 256, 0, stream>>>(a);
    }
    {
        int n4 = (offElems * 4 + 1024) / 16;
        zero_kernel<<<(n4 + 255) / 256, 256, 0, stream>>>(offbase, n4);
    }
    {
        dim3 grd((HWs[3] + 63) / 64, 8, B);
        xs_nhwc<<<grd, 256, 0, stream>>>(x[3], nullptr, xsb[3], Hs[3], Hs[3]);
    }

    const int ktiles[4] = {0, 9, 6, 3};    // off-conv split-K chunking
    const int ksplit[4] = {0, 3, 8, 18};   // main-gemm split-K (divides 72)

    for (int lvl = 3; lvl >= 1; --lvl) {
        int H = Hs[lvl], W = H, HW = HWs[lvl];

        // offset conv (bf16 MFMA split-K, NHWC implicit staging)
        {
            dim3 grd((HW + 63) / 64, 72 / ktiles[lvl], B);
            off_mfma<<<grd, 256, 0, stream>>>(
                owbf[lvl], xsb[lvl], zeros, offbuf[lvl], HW, H, W, ktiles[lvl]);
        }
        // deformable sampling -> cols [b][hw][r*256+c]
        {
            dim3 grd((HW * 8 + 255) / 256, 1, B);
            sampling_kernel<<<grd, 256, 0, stream>>>(
                xsb[lvl], offbuf[lvl], obv[lvl], cols, H, W);
        }
        // main conv: split-K MFMA GEMM into bias-prefilled out
        {
            dim3 grdf((HW + 255) / 256, 256, B);
            bias_fill<<<grdf, 256, 0, stream>>>(out + outOff[lvl], bia[lvl], HW);
            dim3 grd((HW + 127) / 128, 2 * ksplit[lvl], B);
            mfma_gemm<false, true><<<grd, 256, 0, stream>>>(
                wbf[lvl], bia[lvl], cols, zeros, out + outOff[lvl],
                HW, H, W, 2304 / ksplit[lvl]);
        }
        // xs for next-finer level
        {
            int Hn = Hs[lvl - 1];
            dim3 grd((HWs[lvl - 1] + 63) / 64, 8, B);
            xs_nhwc<<<grd, 256, 0, stream>>>(
                x[lvl - 1], out + outOff[lvl], xsb[lvl - 1], Hn, Hn);
        }
    }

    // level 0: implicit NHWC MFMA GEMM
    {
        dim3 grd((HWs[0] + 127) / 128, 2, B);
        mfma_gemm<true, false><<<grd, 256, 0, stream>>>(
            wbf[0], bia[0], xsb[0], zeros, out + outOff[0],
            HWs[0], Hs[0], Hs[0], 2304);
    }
}